// Round 2
// baseline (3424.927 us; speedup 1.0000x reference)
//
#include <hip/hip_runtime.h>
#include <hip/hip_bf16.h>

// StARformer round 1: fp32 I/O (per reference dtypes), fp32 pipeline.
// B=32 N=32 M=64 NL=192 NG=768 HL=6 HG=12. Local rows 65536, global rows 3072.
//
// ws layout (floats), 4 buffers of SZ=12,582,912 -> 201.3 MB total:
//   A  = ws + 0*SZ   ln1 out -> attn Y -> ln2 out
//   Qb = ws + 1*SZ   q -> X1 (post-attn residual)
//   Kb = ws + 2*SZ   k -+-> MLP hidden chunk [32768,768] (= exactly 2*SZ)
//   Vb = ws + 3*SZ   v -+
// xl_out fp32 lives in d_out and feeds the zg projection directly.
// Global phase overlays ws[0 .. 31,457,280) (all free by then).

__device__ __forceinline__ float gelu_exact(float v) {
  return 0.5f * v * (1.f + erff(v * 0.70710678118654752f));
}

// ---------------- LayerNorm: one wave per row ----------------
template<int D>
__global__ __launch_bounds__(256)
void ln_kernel(const float* __restrict__ x, const float* __restrict__ g,
               const float* __restrict__ bb, float* __restrict__ out, int rows)
{
  int wave = threadIdx.x >> 6, lane = threadIdx.x & 63;
  int row = blockIdx.x * 4 + wave;
  if (row >= rows) return;
  const float* xr = x + (size_t)row * D;
  constexpr int E = D / 64;
  float vals[E];
  float s = 0.f;
  #pragma unroll
  for (int e = 0; e < E; ++e) { vals[e] = xr[e * 64 + lane]; s += vals[e]; }
  #pragma unroll
  for (int off = 32; off >= 1; off >>= 1) s += __shfl_xor(s, off);
  float m = s * (1.f / D);
  float s2 = 0.f;
  #pragma unroll
  for (int e = 0; e < E; ++e) { float d = vals[e] - m; s2 += d * d; }
  #pragma unroll
  for (int off = 32; off >= 1; off >>= 1) s2 += __shfl_xor(s2, off);
  float rstd = rsqrtf(s2 * (1.f / D) + 1e-5f);
  float* orow = out + (size_t)row * D;
  #pragma unroll
  for (int e = 0; e < E; ++e) {
    int c = e * 64 + lane;
    orow[c] = (vals[e] - m) * rstd * g[c] + bb[c];
  }
}

// ---------------- Generic tiled GEMM: C = act(A@B + bias) (+res) ----------------
// A,B fp32. 64x64 tile, BK=16, 256 thr, 4x4 per thread. All dims divide evenly.
// ACT: 0=none 1=exact gelu. RES: 0=none 1=add resF.
template<int ACT, int RES>
__global__ __launch_bounds__(256)
void gemm_kernel(const float* __restrict__ A, const float* __restrict__ B,
                 const float* __restrict__ bias, const float* __restrict__ resF,
                 float* __restrict__ C, int M, int N, int K)
{
  __shared__ float At[16][68];   // transposed A tile: At[k][row]
  __shared__ float Bt[16][68];
  const int tid = threadIdx.x;
  const int rowBase = blockIdx.y * 64, colBase = blockIdx.x * 64;
  const int tr = tid >> 4, tc = tid & 15;
  const int lr = tid >> 2, lk = (tid & 3) * 4;   // A staging
  const int bk = tid >> 4, bn = (tid & 15) * 4;  // B staging
  float acc[4][4] = {};
  for (int k0 = 0; k0 < K; k0 += 16) {
    float4 av = *reinterpret_cast<const float4*>(A + (size_t)(rowBase + lr) * K + k0 + lk);
    float4 bv = *reinterpret_cast<const float4*>(B + (size_t)(k0 + bk) * N + colBase + bn);
    At[lk + 0][lr] = av.x; At[lk + 1][lr] = av.y;
    At[lk + 2][lr] = av.z; At[lk + 3][lr] = av.w;
    *reinterpret_cast<float4*>(&Bt[bk][bn]) = bv;
    __syncthreads();
    #pragma unroll
    for (int kk = 0; kk < 16; ++kk) {
      float4 a4 = *reinterpret_cast<const float4*>(&At[kk][tr * 4]);
      float4 b4 = *reinterpret_cast<const float4*>(&Bt[kk][tc * 4]);
      float aa[4] = {a4.x, a4.y, a4.z, a4.w};
      float bb4[4] = {b4.x, b4.y, b4.z, b4.w};
      #pragma unroll
      for (int i = 0; i < 4; ++i)
        #pragma unroll
        for (int j = 0; j < 4; ++j) acc[i][j] += aa[i] * bb4[j];
    }
    __syncthreads();
  }
  const int row0 = rowBase + tr * 4, col0 = colBase + tc * 4;
  #pragma unroll
  for (int i = 0; i < 4; ++i) {
    size_t ro = (size_t)(row0 + i) * N;
    #pragma unroll
    for (int j = 0; j < 4; ++j) {
      int col = col0 + j;
      float v = acc[i][j] + bias[col];
      if (ACT == 1) v = gelu_exact(v);
      if (RES == 1) v += resF[ro + col];
      C[ro + col] = v;
    }
  }
}

// ---------------- Attention: one block per (seq, head), causal ----------------
// Q,K,V,Y fp32 [nseq*L, nh*HD]. 4 waves, wave w handles rows w, w+4, ...
template<int L, int HD>
__global__ __launch_bounds__(256)
void attn_kernel(const float* __restrict__ Qp, const float* __restrict__ Kp,
                 const float* __restrict__ Vp, float* __restrict__ Yp,
                 int nh, int D)
{
  __shared__ float kl[L][HD];
  __shared__ float vl[L][HD];
  const int bh = blockIdx.x;
  const int b = bh / nh, h = bh % nh;
  const size_t base = (size_t)b * L * D + (size_t)h * HD;
  for (int idx = threadIdx.x; idx < L * HD; idx += 256) {
    int j = idx / HD, d = idx % HD;
    kl[j][d] = Kp[base + (size_t)j * D + d];
    vl[j][d] = Vp[base + (size_t)j * D + d];
  }
  __syncthreads();
  const int lane = threadIdx.x & 63, wave = threadIdx.x >> 6;
  const float scale = (HD == 32) ? 0.17677669529663687f : 0.125f;
  const int j1 = lane + 64;
  for (int i = wave; i < L; i += 4) {
    float qreg = (lane < HD) ? Qp[base + (size_t)i * D + lane] : 0.f;
    float s0 = 0.f, s1 = 0.f;
    #pragma unroll
    for (int d = 0; d < HD; ++d) {
      float qv = __shfl(qreg, d);
      s0 += qv * kl[lane][d];
      if (L > 64) { if (j1 < L) s1 += qv * kl[(j1 < L) ? j1 : 0][d]; }
    }
    s0 *= scale; s1 *= scale;
    bool val0 = (lane <= i);
    bool val1 = (L > 64) && (j1 < L) && (j1 <= i);
    float m = val0 ? s0 : -1e30f;
    if (L > 64) m = fmaxf(m, val1 ? s1 : -1e30f);
    #pragma unroll
    for (int off = 32; off >= 1; off >>= 1) m = fmaxf(m, __shfl_xor(m, off));
    float p0 = val0 ? expf(s0 - m) : 0.f;
    float p1 = val1 ? expf(s1 - m) : 0.f;
    float l = p0 + p1;
    #pragma unroll
    for (int off = 32; off >= 1; off >>= 1) l += __shfl_xor(l, off);
    float inv = 1.f / l;
    float y = 0.f;
    const int dd = (lane < HD) ? lane : 0;
    for (int j = 0; j < L; ++j) {
      float pv = (j < 64) ? __shfl(p0, j) : __shfl(p1, j - 64);
      y += pv * vl[j][dd];
    }
    if (lane < HD) Yp[base + (size_t)i * D + lane] = y * inv;
  }
}

// ---------------- zg interleave: [B,96,768] = proj | xg0 | xg1 ----------------
__global__ __launch_bounds__(256)
void interleave_kernel(const float* __restrict__ zg, const float* __restrict__ xg,
                       float* __restrict__ z)
{
  int idx = blockIdx.x * 256 + threadIdx.x;   // over 3072*768
  int c = idx % 768;
  int tok = idx / 768;
  int b = tok / 96, r = tok % 96;
  int n = r / 3, t = r % 3;
  float v;
  if (t == 0) v = zg[((size_t)b * 32 + n) * 768 + c];
  else        v = xg[((size_t)b * 64 + 2 * n + (t - 1)) * 768 + c];
  z[idx] = v;
}

// ---------------- final xg_out gather: drop token 0 of each triplet ----------------
__global__ __launch_bounds__(256)
void gather_kernel(const float* __restrict__ zfin, float* __restrict__ dst)
{
  int idx = blockIdx.x * 256 + threadIdx.x;   // over 32*64*768
  int c = idx % 768;
  int t = (idx / 768) % 64;
  int b = idx / (768 * 64);
  int n = t >> 1, s = t & 1;
  dst[idx] = zfin[((size_t)b * 96 + 3 * n + 1 + s) * 768 + c];
}

extern "C" void kernel_launch(void* const* d_in, const int* in_sizes, int n_in,
                              void* d_out, int out_size, void* d_ws, size_t ws_size,
                              hipStream_t stream) {
  const float* xl = (const float*)d_in[0];
  const float* xg = (const float*)d_in[1];
  const float* l_ln1_w = (const float*)d_in[2];  const float* l_ln1_b = (const float*)d_in[3];
  const float* l_ln2_w = (const float*)d_in[4];  const float* l_ln2_b = (const float*)d_in[5];
  const float* l_wq = (const float*)d_in[6];     const float* l_bq = (const float*)d_in[7];
  const float* l_wk = (const float*)d_in[8];     const float* l_bk = (const float*)d_in[9];
  const float* l_wv = (const float*)d_in[10];    const float* l_bv = (const float*)d_in[11];
  const float* l_wo = (const float*)d_in[12];    const float* l_bo = (const float*)d_in[13];
  const float* l_w1 = (const float*)d_in[14];    const float* l_b1 = (const float*)d_in[15];
  const float* l_w2 = (const float*)d_in[16];    const float* l_b2 = (const float*)d_in[17];
  const float* g_ln1_w = (const float*)d_in[18]; const float* g_ln1_b = (const float*)d_in[19];
  const float* g_ln2_w = (const float*)d_in[20]; const float* g_ln2_b = (const float*)d_in[21];
  const float* g_wq = (const float*)d_in[22];    const float* g_bq = (const float*)d_in[23];
  const float* g_wk = (const float*)d_in[24];    const float* g_bk = (const float*)d_in[25];
  const float* g_wv = (const float*)d_in[26];    const float* g_bv = (const float*)d_in[27];
  const float* g_wo = (const float*)d_in[28];    const float* g_bo = (const float*)d_in[29];
  const float* g_w1 = (const float*)d_in[30];    const float* g_b1 = (const float*)d_in[31];
  const float* g_w2 = (const float*)d_in[32];    const float* g_b2 = (const float*)d_in[33];
  const float* dw   = (const float*)d_in[34];    const float* db   = (const float*)d_in[35];

  float* outL = (float*)d_out;                 // xl_out [65536,192] fp32
  float* outG = outL + 12582912;               // xg_out [2048,768]  fp32

  float* ws = (float*)d_ws;
  const size_t SZ = 65536ull * 192;            // 12,582,912 floats
  float* A  = ws;
  float* Qb = ws + SZ;
  float* Kb = ws + 2 * SZ;
  float* Vb = ws + 3 * SZ;
  float* HIDL = Kb;                            // [32768,768] = K+V regions exactly
  // global overlays (everything in ws is free by the global phase)
  float* ZG   = ws + 0;                        // [1024,768]
  float* Z    = ws + 786432;                   // [3072,768] residual stream
  float* LNG  = ws + 3145728;
  float* QG   = ws + 5505024;
  float* KG   = ws + 7864320;
  float* VG   = ws + 10223616;
  float* YG   = ws + 12582912;
  float* X1G  = ws + 14942208;
  float* HLNG = ws + 17301504;
  float* HIDG = ws + 19660800;                 // [3072,3072]
  float* OUTG = ws + 29097984;                 // [3072,768]

  // ---- local block ----
  ln_kernel<192><<<16384, 256, 0, stream>>>(xl, l_ln1_w, l_ln1_b, A, 65536);
  gemm_kernel<0,0><<<dim3(3,1024), 256, 0, stream>>>(A, l_wq, l_bq, nullptr, Qb, 65536, 192, 192);
  gemm_kernel<0,0><<<dim3(3,1024), 256, 0, stream>>>(A, l_wk, l_bk, nullptr, Kb, 65536, 192, 192);
  gemm_kernel<0,0><<<dim3(3,1024), 256, 0, stream>>>(A, l_wv, l_bv, nullptr, Vb, 65536, 192, 192);
  attn_kernel<64,32><<<6144, 256, 0, stream>>>(Qb, Kb, Vb, A, 6, 192);
  gemm_kernel<0,1><<<dim3(3,1024), 256, 0, stream>>>(A, l_wo, l_bo, xl, Qb, 65536, 192, 192);  // X1 -> Qb
  ln_kernel<192><<<16384, 256, 0, stream>>>(Qb, l_ln2_w, l_ln2_b, A, 65536);
  for (int h = 0; h < 2; ++h) {
    size_t ro = (size_t)h * 32768 * 192;
    size_t rh = (size_t)h * 32768;
    gemm_kernel<1,0><<<dim3(12,512), 256, 0, stream>>>(A + ro, l_w1, l_b1, nullptr, HIDL, 32768, 768, 192);
    gemm_kernel<0,1><<<dim3(3,512), 256, 0, stream>>>(HIDL, l_w2, l_b2, Qb + ro, outL + ro, 32768, 192, 768);
    (void)rh;
  }
  // ---- group summary projection + interleave (reads xl_out from d_out) ----
  gemm_kernel<0,0><<<dim3(12,16), 256, 0, stream>>>(outL, dw, db, nullptr, ZG, 1024, 768, 12288);
  interleave_kernel<<<9216, 256, 0, stream>>>(ZG, xg, Z);
  // ---- global block ----
  ln_kernel<768><<<768, 256, 0, stream>>>(Z, g_ln1_w, g_ln1_b, LNG, 3072);
  gemm_kernel<0,0><<<dim3(12,48), 256, 0, stream>>>(LNG, g_wq, g_bq, nullptr, QG, 3072, 768, 768);
  gemm_kernel<0,0><<<dim3(12,48), 256, 0, stream>>>(LNG, g_wk, g_bk, nullptr, KG, 3072, 768, 768);
  gemm_kernel<0,0><<<dim3(12,48), 256, 0, stream>>>(LNG, g_wv, g_bv, nullptr, VG, 3072, 768, 768);
  attn_kernel<96,64><<<384, 256, 0, stream>>>(QG, KG, VG, YG, 12, 768);
  gemm_kernel<0,1><<<dim3(12,48), 256, 0, stream>>>(YG, g_wo, g_bo, Z, X1G, 3072, 768, 768);
  ln_kernel<768><<<768, 256, 0, stream>>>(X1G, g_ln2_w, g_ln2_b, HLNG, 3072);
  gemm_kernel<1,0><<<dim3(48,48), 256, 0, stream>>>(HLNG, g_w1, g_b1, nullptr, HIDG, 3072, 3072, 768);
  gemm_kernel<0,1><<<dim3(12,48), 256, 0, stream>>>(HIDG, g_w2, g_b2, X1G, OUTG, 3072, 768, 3072);
  gather_kernel<<<6144, 256, 0, stream>>>(OUTG, outG);
}

// Round 3
// 1582.221 us; speedup vs baseline: 2.1646x; 2.1646x over previous
//
#include <hip/hip_runtime.h>
#include <hip/hip_bf16.h>

// StARformer round 2: bf16 MFMA GEMMs (16x16x32), fp32 residual stream.
// All GEMM B-operands are weights, converted fp32->bf16 TRANSPOSED [N][K] per
// call. QKV fused (local N=576, global N=2304). zg-proj split-K=8 + reduce.

typedef unsigned short ushort;
typedef __bf16 bf16x8 __attribute__((ext_vector_type(8)));
typedef float f32x4 __attribute__((ext_vector_type(4)));

__device__ __forceinline__ float us2f(ushort u) {
  union { unsigned i; float f; } w; w.i = ((unsigned)u) << 16; return w.f;
}
__device__ __forceinline__ ushort f2us(float f) {
  __hip_bfloat16 h = __float2bfloat16(f);
  return *reinterpret_cast<ushort*>(&h);
}
__device__ __forceinline__ float gelu_exact(float v) {
  return 0.5f * v * (1.f + erff(v * 0.70710678118654752f));
}
__device__ __forceinline__ void gload16(const ushort* g, ushort* l) {
  __builtin_amdgcn_global_load_lds(
      (const __attribute__((address_space(1))) void*)g,
      (__attribute__((address_space(3))) void*)l, 16, 0, 0);
}

// ---------- transpose+convert: Wt[(rowOff+n)*dstStride+k] = bf16(W[k*N+n]) ----------
__global__ __launch_bounds__(256)
void transp_kernel(const float* __restrict__ W, ushort* __restrict__ Wt,
                   int K, int N, int dstStride, int rowOff)
{
  __shared__ float t[64][65];
  int n0 = blockIdx.x * 64, k0 = blockIdx.y * 64;
  int c = threadIdx.x & 63, r = threadIdx.x >> 6;
  #pragma unroll
  for (int i = 0; i < 16; ++i) {
    int kr = r + i * 4;
    t[kr][c] = W[(size_t)(k0 + kr) * N + n0 + c];
  }
  __syncthreads();
  #pragma unroll
  for (int i = 0; i < 16; ++i) {
    int nr = r + i * 4;
    Wt[(size_t)(rowOff + n0 + nr) * dstStride + k0 + c] = f2us(t[c][nr]);
  }
}

// ---------- pack 3 bias vectors ----------
__global__ __launch_bounds__(256)
void pack3_kernel(float* dst, const float* a, int na, const float* b, int nb,
                  const float* c, int nc)
{
  int i = blockIdx.x * 256 + threadIdx.x;
  if (i >= na + nb + nc) return;
  dst[i] = (i < na) ? a[i] : (i < na + nb ? b[i - na] : c[i - na - nb]);
}

// ---------- LayerNorm: one wave per row, fp32 in, bf16 out ----------
template<int D>
__global__ __launch_bounds__(256)
void ln_kernel(const float* __restrict__ x, const float* __restrict__ g,
               const float* __restrict__ bb, ushort* __restrict__ out, int rows)
{
  int wave = threadIdx.x >> 6, lane = threadIdx.x & 63;
  int row = blockIdx.x * 4 + wave;
  if (row >= rows) return;
  const float* xr = x + (size_t)row * D;
  constexpr int E = D / 64;
  float vals[E];
  float s = 0.f;
  #pragma unroll
  for (int e = 0; e < E; ++e) { vals[e] = xr[e * 64 + lane]; s += vals[e]; }
  #pragma unroll
  for (int off = 32; off >= 1; off >>= 1) s += __shfl_xor(s, off);
  float m = s * (1.f / D);
  float s2 = 0.f;
  #pragma unroll
  for (int e = 0; e < E; ++e) { float d = vals[e] - m; s2 += d * d; }
  #pragma unroll
  for (int off = 32; off >= 1; off >>= 1) s2 += __shfl_xor(s2, off);
  float rstd = rsqrtf(s2 * (1.f / D) + 1e-5f);
  ushort* orow = out + (size_t)row * D;
  #pragma unroll
  for (int e = 0; e < E; ++e) {
    int c = e * 64 + lane;
    orow[c] = f2us((vals[e] - m) * rstd * g[c] + bb[c]);
  }
}

// ---------- MFMA GEMM: BM=128 BN=64 BK=32, 4 waves (2x2), wave=64x32 ----------
// A bf16 [M][K] row-major; Bt bf16 [N][K] (transposed weight). C = act(A@B+bias)(+res).
// SPLITK: blockIdx.z selects K-chunk, writes fp32 partial at Cf + z*M*N (no bias/act/res).
template<int ACT, int RES, int OUTF, int OUTB, int BIAS, int SPLITK>
__global__ __launch_bounds__(256)
void mgemm(const ushort* __restrict__ A, const ushort* __restrict__ Bt,
           const float* __restrict__ bias, const float* __restrict__ resF,
           float* __restrict__ Cf, ushort* __restrict__ Cb,
           int M, int N, int K, int kChunk)
{
  __shared__ __align__(16) ushort Asm[128 * 32];
  __shared__ __align__(16) ushort Bsm[64 * 32];
  const int tid = threadIdx.x;
  const int wave = tid >> 6, lane = tid & 63;
  const int quad = lane >> 4, lm = lane & 15;
  const int rowBase = blockIdx.y * 128, colBase = blockIdx.x * 64;
  const int wrow = (wave & 1) * 64, wcol = (wave >> 1) * 32;
  const int srow = lane >> 2, skcol = (lane & 3) * 8;   // staging lane map

  f32x4 acc[4][2] = {};
  const int kbeg = SPLITK ? blockIdx.z * kChunk : 0;
  const int kend = kbeg + (SPLITK ? kChunk : K);

  for (int k0 = kbeg; k0 < kend; k0 += 32) {
    // stage: 12 units of 16 rows (8 A + 4 B), 3 per wave; LDS dst wave-uniform
    #pragma unroll
    for (int uu = 0; uu < 3; ++uu) {
      int u = wave * 3 + uu;
      if (u < 8) {
        const ushort* gp = A + (size_t)(rowBase + u * 16 + srow) * K + k0 + skcol;
        gload16(gp, &Asm[u * 512]);
      } else {
        int v = u - 8;
        const ushort* gp = Bt + (size_t)(colBase + v * 16 + srow) * K + k0 + skcol;
        gload16(gp, &Bsm[v * 512]);
      }
    }
    __syncthreads();
    bf16x8 af[4], bfr[2];
    #pragma unroll
    for (int r2 = 0; r2 < 4; ++r2)
      af[r2] = *reinterpret_cast<const bf16x8*>(&Asm[(wrow + r2 * 16 + lm) * 32 + quad * 8]);
    #pragma unroll
    for (int c2 = 0; c2 < 2; ++c2)
      bfr[c2] = *reinterpret_cast<const bf16x8*>(&Bsm[(wcol + c2 * 16 + lm) * 32 + quad * 8]);
    #pragma unroll
    for (int r2 = 0; r2 < 4; ++r2)
      #pragma unroll
      for (int c2 = 0; c2 < 2; ++c2)
        acc[r2][c2] = __builtin_amdgcn_mfma_f32_16x16x32_bf16(af[r2], bfr[c2], acc[r2][c2], 0, 0, 0);
    __syncthreads();
  }

  // epilogue: D col = lm, row = quad*4 + reg
  const size_t zoff = SPLITK ? (size_t)blockIdx.z * M * N : 0;
  #pragma unroll
  for (int r2 = 0; r2 < 4; ++r2) {
    #pragma unroll
    for (int c2 = 0; c2 < 2; ++c2) {
      int col = colBase + wcol + c2 * 16 + lm;
      int row0 = rowBase + wrow + r2 * 16 + quad * 4;
      #pragma unroll
      for (int g = 0; g < 4; ++g) {
        float v = acc[r2][c2][g];
        size_t idx = (size_t)(row0 + g) * N + col;
        if (BIAS) v += bias[col];
        if (ACT == 1) v = gelu_exact(v);
        if (RES) v += resF[idx];
        if (OUTF) Cf[zoff + idx] = v;
        if (OUTB) Cb[idx] = f2us(v);
      }
    }
  }
}

// ---------- split-K reduce for zg: ZG = sum_s P[s] + bias ----------
__global__ __launch_bounds__(256)
void reduce8_kernel(const float* __restrict__ P, const float* __restrict__ db,
                    float* __restrict__ ZG)
{
  int i = blockIdx.x * 256 + threadIdx.x;   // 1024*768
  float s = db[i % 768];
  #pragma unroll
  for (int k = 0; k < 8; ++k) s += P[i + k * 786432];
  ZG[i] = s;
}

// ---------- attention: bf16 packed-QKV in, bf16 Y out, fp32 math ----------
template<int L, int HD>
__global__ __launch_bounds__(256)
void attn_kernel(const ushort* __restrict__ QKV, ushort* __restrict__ Yp,
                 int nh, int DS, int DY, int offQ, int offK, int offV)
{
  __shared__ float kl[L][HD];
  __shared__ float vl[L][HD];
  const int bh = blockIdx.x;
  const int b = bh / nh, h = bh % nh;
  const size_t rowb = (size_t)b * L * DS;
  const int hb = h * HD;
  for (int idx = threadIdx.x; idx < L * HD; idx += 256) {
    int j = idx / HD, d = idx % HD;
    kl[j][d] = us2f(QKV[rowb + (size_t)j * DS + offK + hb + d]);
    vl[j][d] = us2f(QKV[rowb + (size_t)j * DS + offV + hb + d]);
  }
  __syncthreads();
  const int lane = threadIdx.x & 63, wave = threadIdx.x >> 6;
  const float scale = (HD == 32) ? 0.17677669529663687f : 0.125f;
  const int j1 = lane + 64;
  for (int i = wave; i < L; i += 4) {
    float qreg = (lane < HD) ? us2f(QKV[rowb + (size_t)i * DS + offQ + hb + lane]) : 0.f;
    float s0 = 0.f, s1 = 0.f;
    #pragma unroll
    for (int d = 0; d < HD; ++d) {
      float qv = __shfl(qreg, d);
      s0 += qv * kl[lane][d];
      if (L > 64) { if (j1 < L) s1 += qv * kl[(j1 < L) ? j1 : 0][d]; }
    }
    s0 *= scale; s1 *= scale;
    bool val0 = (lane <= i);
    bool val1 = (L > 64) && (j1 < L) && (j1 <= i);
    float m = val0 ? s0 : -1e30f;
    if (L > 64) m = fmaxf(m, val1 ? s1 : -1e30f);
    #pragma unroll
    for (int off = 32; off >= 1; off >>= 1) m = fmaxf(m, __shfl_xor(m, off));
    float p0 = val0 ? expf(s0 - m) : 0.f;
    float p1 = val1 ? expf(s1 - m) : 0.f;
    float l = p0 + p1;
    #pragma unroll
    for (int off = 32; off >= 1; off >>= 1) l += __shfl_xor(l, off);
    float inv = 1.f / l;
    float y = 0.f;
    const int dd = (lane < HD) ? lane : 0;
    for (int j = 0; j < L; ++j) {
      float pv = (j < 64) ? __shfl(p0, j) : __shfl(p1, j - 64);
      y += pv * vl[j][dd];
    }
    if (lane < HD) Yp[(size_t)b * L * DY + (size_t)i * DY + hb + lane] = f2us(y * inv);
  }
}

// ---------- zg interleave (fp32) ----------
__global__ __launch_bounds__(256)
void interleave_kernel(const float* __restrict__ zg, const float* __restrict__ xg,
                       float* __restrict__ z)
{
  int idx = blockIdx.x * 256 + threadIdx.x;   // 3072*768
  int c = idx % 768;
  int tok = idx / 768;
  int b = tok / 96, r = tok % 96;
  int n = r / 3, t = r % 3;
  z[idx] = (t == 0) ? zg[((size_t)b * 32 + n) * 768 + c]
                    : xg[((size_t)b * 64 + 2 * n + (t - 1)) * 768 + c];
}

// ---------- final gather (fp32) ----------
__global__ __launch_bounds__(256)
void gather_kernel(const float* __restrict__ zfin, float* __restrict__ dst)
{
  int idx = blockIdx.x * 256 + threadIdx.x;   // 32*64*768
  int c = idx % 768;
  int t = (idx / 768) % 64;
  int b = idx / (768 * 64);
  int n = t >> 1, s = t & 1;
  dst[idx] = zfin[((size_t)b * 96 + 3 * n + 1 + s) * 768 + c];
}

extern "C" void kernel_launch(void* const* d_in, const int* in_sizes, int n_in,
                              void* d_out, int out_size, void* d_ws, size_t ws_size,
                              hipStream_t stream) {
  const float* xl = (const float*)d_in[0];
  const float* xg = (const float*)d_in[1];
  const float* l_ln1_w = (const float*)d_in[2];  const float* l_ln1_b = (const float*)d_in[3];
  const float* l_ln2_w = (const float*)d_in[4];  const float* l_ln2_b = (const float*)d_in[5];
  const float* l_wq = (const float*)d_in[6];     const float* l_bq = (const float*)d_in[7];
  const float* l_wk = (const float*)d_in[8];     const float* l_bk = (const float*)d_in[9];
  const float* l_wv = (const float*)d_in[10];    const float* l_bv = (const float*)d_in[11];
  const float* l_wo = (const float*)d_in[12];    const float* l_bo = (const float*)d_in[13];
  const float* l_w1 = (const float*)d_in[14];    const float* l_b1 = (const float*)d_in[15];
  const float* l_w2 = (const float*)d_in[16];    const float* l_b2 = (const float*)d_in[17];
  const float* g_ln1_w = (const float*)d_in[18]; const float* g_ln1_b = (const float*)d_in[19];
  const float* g_ln2_w = (const float*)d_in[20]; const float* g_ln2_b = (const float*)d_in[21];
  const float* g_wq = (const float*)d_in[22];    const float* g_bq = (const float*)d_in[23];
  const float* g_wk = (const float*)d_in[24];    const float* g_bk = (const float*)d_in[25];
  const float* g_wv = (const float*)d_in[26];    const float* g_bv = (const float*)d_in[27];
  const float* g_wo = (const float*)d_in[28];    const float* g_bo = (const float*)d_in[29];
  const float* g_w1 = (const float*)d_in[30];    const float* g_b1 = (const float*)d_in[31];
  const float* g_w2 = (const float*)d_in[32];    const float* g_b2 = (const float*)d_in[33];
  const float* dw   = (const float*)d_in[34];    const float* db   = (const float*)d_in[35];

  float* outL = (float*)d_out;                 // xl_out [65536,192] fp32
  float* outG = outL + 12582912;               // xg_out [2048,768]  fp32

  char* W = (char*)d_ws;
  ushort* A_bf   = (ushort*)(W + 0);           // 25.2MB: ln1 out / Y / ln2 out
  ushort* QKVl   = (ushort*)(W + 25165824);    // 75.5MB packed qkv [65536][576]
  ushort* HIDl   = (ushort*)(W + 25165824);    // chunk [32768][768] (reuses QKV)
  ushort* XLb    = (ushort*)(W + 75497472);    // xl_out bf16 [1024][12288]
  float*  X1     = (float*)(W + 100663296);    // 50.3MB fp32 residual
  ushort* wqkv_t = (ushort*)(W + 150994944);   // [576][192]
  ushort* wo_t   = (ushort*)(W + 151216128);
  ushort* w1_t   = (ushort*)(W + 151289856);   // [768][192]
  ushort* w2_t   = (ushort*)(W + 151584768);   // [192][768]
  ushort* wd_t   = (ushort*)(W + 151879680);   // [768][12288]
  ushort* wgqkv_t= (ushort*)(W + 170754048);   // [2304][768]
  ushort* wgo_t  = (ushort*)(W + 174292992);
  ushort* wg1_t  = (ushort*)(W + 175472640);   // [3072][768]
  ushort* wg2_t  = (ushort*)(W + 180191232);   // [768][3072]
  float*  bqkv_l = (float*)(W + 184909824);
  float*  bqkv_g = (float*)(W + 184912128);
  // global phase overlays (local-phase low region is dead by then)
  float*  ZGP  = (float*)(W + 0);              // 8 partials [1024][768]
  float*  ZG   = (float*)(W + 25165824);
  float*  Z    = (float*)(W + 28311552);       // [3072][768] residual
  ushort* LNG  = (ushort*)(W + 37748736);
  ushort* QKVg = (ushort*)(W + 42467328);      // [3072][2304]
  ushort* YG   = (ushort*)(W + 56623104);
  float*  X1G  = (float*)(W + 61341696);
  ushort* HLNG = (ushort*)(W + 70778880);      // ends exactly at XLb
  ushort* HIDg = (ushort*)(W + 100663296);     // [3072][3072] (X1 region, free)
  float*  OUTG = (float*)(W + 119537664);

  // ---- weight conversion (transposed bf16) + bias packs ----
  transp_kernel<<<dim3(3,3),   256, 0, stream>>>(l_wq, wqkv_t, 192, 192, 192, 0);
  transp_kernel<<<dim3(3,3),   256, 0, stream>>>(l_wk, wqkv_t, 192, 192, 192, 192);
  transp_kernel<<<dim3(3,3),   256, 0, stream>>>(l_wv, wqkv_t, 192, 192, 192, 384);
  transp_kernel<<<dim3(3,3),   256, 0, stream>>>(l_wo, wo_t,   192, 192, 192, 0);
  transp_kernel<<<dim3(12,3),  256, 0, stream>>>(l_w1, w1_t,   192, 768, 192, 0);
  transp_kernel<<<dim3(3,12),  256, 0, stream>>>(l_w2, w2_t,   768, 192, 768, 0);
  transp_kernel<<<dim3(12,192),256, 0, stream>>>(dw,   wd_t,   12288, 768, 12288, 0);
  transp_kernel<<<dim3(12,12), 256, 0, stream>>>(g_wq, wgqkv_t, 768, 768, 768, 0);
  transp_kernel<<<dim3(12,12), 256, 0, stream>>>(g_wk, wgqkv_t, 768, 768, 768, 768);
  transp_kernel<<<dim3(12,12), 256, 0, stream>>>(g_wv, wgqkv_t, 768, 768, 768, 1536);
  transp_kernel<<<dim3(12,12), 256, 0, stream>>>(g_wo, wgo_t,  768, 768, 768, 0);
  transp_kernel<<<dim3(48,12), 256, 0, stream>>>(g_w1, wg1_t,  768, 3072, 768, 0);
  transp_kernel<<<dim3(12,48), 256, 0, stream>>>(g_w2, wg2_t,  3072, 768, 3072, 0);
  pack3_kernel<<<3, 256, 0, stream>>>(bqkv_l, l_bq, 192, l_bk, 192, l_bv, 192);
  pack3_kernel<<<9, 256, 0, stream>>>(bqkv_g, g_bq, 768, g_bk, 768, g_bv, 768);

  // ---- local block ----
  ln_kernel<192><<<16384, 256, 0, stream>>>(xl, l_ln1_w, l_ln1_b, A_bf, 65536);
  mgemm<0,0,0,1,1,0><<<dim3(9,512), 256, 0, stream>>>(A_bf, wqkv_t, bqkv_l, nullptr, nullptr, QKVl, 65536, 576, 192, 0);
  attn_kernel<64,32><<<6144, 256, 0, stream>>>(QKVl, A_bf, 6, 576, 192, 0, 192, 384);
  mgemm<0,1,1,0,1,0><<<dim3(3,512), 256, 0, stream>>>(A_bf, wo_t, l_bo, xl, X1, nullptr, 65536, 192, 192, 0);
  ln_kernel<192><<<16384, 256, 0, stream>>>(X1, l_ln2_w, l_ln2_b, A_bf, 65536);
  for (int h = 0; h < 2; ++h) {
    size_t ro = (size_t)h * 32768 * 192;
    mgemm<1,0,0,1,1,0><<<dim3(12,256), 256, 0, stream>>>(A_bf + ro, w1_t, l_b1, nullptr, nullptr, HIDl, 32768, 768, 192, 0);
    mgemm<0,1,1,1,1,0><<<dim3(3,256), 256, 0, stream>>>(HIDl, w2_t, l_b2, X1 + ro, outL + ro, XLb + ro, 32768, 192, 768, 0);
  }
  // ---- group summary projection (split-K=8) + interleave ----
  mgemm<0,0,1,0,0,1><<<dim3(12,8,8), 256, 0, stream>>>(XLb, wd_t, nullptr, nullptr, ZGP, nullptr, 1024, 768, 12288, 1536);
  reduce8_kernel<<<3072, 256, 0, stream>>>(ZGP, db, ZG);
  interleave_kernel<<<9216, 256, 0, stream>>>(ZG, xg, Z);
  // ---- global block ----
  ln_kernel<768><<<768, 256, 0, stream>>>(Z, g_ln1_w, g_ln1_b, LNG, 3072);
  mgemm<0,0,0,1,1,0><<<dim3(36,24), 256, 0, stream>>>(LNG, wgqkv_t, bqkv_g, nullptr, nullptr, QKVg, 3072, 2304, 768, 0);
  attn_kernel<96,64><<<384, 256, 0, stream>>>(QKVg, YG, 12, 2304, 768, 0, 768, 1536);
  mgemm<0,1,1,0,1,0><<<dim3(12,24), 256, 0, stream>>>(YG, wgo_t, g_bo, Z, X1G, nullptr, 3072, 768, 768, 0);
  ln_kernel<768><<<768, 256, 0, stream>>>(X1G, g_ln2_w, g_ln2_b, HLNG, 3072);
  mgemm<1,0,0,1,1,0><<<dim3(48,24), 256, 0, stream>>>(HLNG, wg1_t, g_b1, nullptr, nullptr, HIDg, 3072, 3072, 768, 0);
  mgemm<0,1,1,0,1,0><<<dim3(12,24), 256, 0, stream>>>(HIDg, wg2_t, g_b2, X1G, OUTG, nullptr, 3072, 768, 3072, 0);
  gather_kernel<<<6144, 256, 0, stream>>>(OUTG, outG);
}

// Round 4
// 741.750 us; speedup vs baseline: 4.6174x; 2.1331x over previous
//
#include <hip/hip_runtime.h>
#include <hip/hip_bf16.h>

// StARformer round 3: MFMA fused attention (both tiers) + round-2 bf16 MFMA GEMMs.

typedef unsigned short ushort;
typedef __bf16 bf16x8 __attribute__((ext_vector_type(8)));
typedef float f32x4 __attribute__((ext_vector_type(4)));

__device__ __forceinline__ float us2f(ushort u) {
  union { unsigned i; float f; } w; w.i = ((unsigned)u) << 16; return w.f;
}
__device__ __forceinline__ ushort f2us(float f) {
  __hip_bfloat16 h = __float2bfloat16(f);
  return *reinterpret_cast<ushort*>(&h);
}
__device__ __forceinline__ float gelu_exact(float v) {
  return 0.5f * v * (1.f + erff(v * 0.70710678118654752f));
}
__device__ __forceinline__ void gload16(const ushort* g, ushort* l) {
  __builtin_amdgcn_global_load_lds(
      (const __attribute__((address_space(1))) void*)g,
      (__attribute__((address_space(3))) void*)l, 16, 0, 0);
}

// ---------- transpose+convert: Wt[(rowOff+n)*dstStride+k] = bf16(W[k*N+n]) ----------
__global__ __launch_bounds__(256)
void transp_kernel(const float* __restrict__ W, ushort* __restrict__ Wt,
                   int K, int N, int dstStride, int rowOff)
{
  __shared__ float t[64][65];
  int n0 = blockIdx.x * 64, k0 = blockIdx.y * 64;
  int c = threadIdx.x & 63, r = threadIdx.x >> 6;
  #pragma unroll
  for (int i = 0; i < 16; ++i) {
    int kr = r + i * 4;
    t[kr][c] = W[(size_t)(k0 + kr) * N + n0 + c];
  }
  __syncthreads();
  #pragma unroll
  for (int i = 0; i < 16; ++i) {
    int nr = r + i * 4;
    Wt[(size_t)(rowOff + n0 + nr) * dstStride + k0 + c] = f2us(t[c][nr]);
  }
}

// ---------- pack 3 bias vectors ----------
__global__ __launch_bounds__(256)
void pack3_kernel(float* dst, const float* a, int na, const float* b, int nb,
                  const float* c, int nc)
{
  int i = blockIdx.x * 256 + threadIdx.x;
  if (i >= na + nb + nc) return;
  dst[i] = (i < na) ? a[i] : (i < na + nb ? b[i - na] : c[i - na - nb]);
}

// ---------- LayerNorm: one wave per row, fp32 in, bf16 out ----------
template<int D>
__global__ __launch_bounds__(256)
void ln_kernel(const float* __restrict__ x, const float* __restrict__ g,
               const float* __restrict__ bb, ushort* __restrict__ out, int rows)
{
  int wave = threadIdx.x >> 6, lane = threadIdx.x & 63;
  int row = blockIdx.x * 4 + wave;
  if (row >= rows) return;
  const float* xr = x + (size_t)row * D;
  constexpr int E = D / 64;
  float vals[E];
  float s = 0.f;
  #pragma unroll
  for (int e = 0; e < E; ++e) { vals[e] = xr[e * 64 + lane]; s += vals[e]; }
  #pragma unroll
  for (int off = 32; off >= 1; off >>= 1) s += __shfl_xor(s, off);
  float m = s * (1.f / D);
  float s2 = 0.f;
  #pragma unroll
  for (int e = 0; e < E; ++e) { float d = vals[e] - m; s2 += d * d; }
  #pragma unroll
  for (int off = 32; off >= 1; off >>= 1) s2 += __shfl_xor(s2, off);
  float rstd = rsqrtf(s2 * (1.f / D) + 1e-5f);
  ushort* orow = out + (size_t)row * D;
  #pragma unroll
  for (int e = 0; e < E; ++e) {
    int c = e * 64 + lane;
    orow[c] = f2us((vals[e] - m) * rstd * g[c] + bb[c]);
  }
}

// ---------- MFMA GEMM: BM=128 BN=64 BK=32, 4 waves (2x2), wave=64x32 ----------
template<int ACT, int RES, int OUTF, int OUTB, int BIAS, int SPLITK>
__global__ __launch_bounds__(256)
void mgemm(const ushort* __restrict__ A, const ushort* __restrict__ Bt,
           const float* __restrict__ bias, const float* __restrict__ resF,
           float* __restrict__ Cf, ushort* __restrict__ Cb,
           int M, int N, int K, int kChunk)
{
  __shared__ __align__(16) ushort Asm[128 * 32];
  __shared__ __align__(16) ushort Bsm[64 * 32];
  const int tid = threadIdx.x;
  const int wave = tid >> 6, lane = tid & 63;
  const int quad = lane >> 4, lm = lane & 15;
  const int rowBase = blockIdx.y * 128, colBase = blockIdx.x * 64;
  const int wrow = (wave & 1) * 64, wcol = (wave >> 1) * 32;
  const int srow = lane >> 2, skcol = (lane & 3) * 8;

  f32x4 acc[4][2] = {};
  const int kbeg = SPLITK ? blockIdx.z * kChunk : 0;
  const int kend = kbeg + (SPLITK ? kChunk : K);

  for (int k0 = kbeg; k0 < kend; k0 += 32) {
    #pragma unroll
    for (int uu = 0; uu < 3; ++uu) {
      int u = wave * 3 + uu;
      if (u < 8) {
        const ushort* gp = A + (size_t)(rowBase + u * 16 + srow) * K + k0 + skcol;
        gload16(gp, &Asm[u * 512]);
      } else {
        int v = u - 8;
        const ushort* gp = Bt + (size_t)(colBase + v * 16 + srow) * K + k0 + skcol;
        gload16(gp, &Bsm[v * 512]);
      }
    }
    __syncthreads();
    bf16x8 af[4], bfr[2];
    #pragma unroll
    for (int r2 = 0; r2 < 4; ++r2)
      af[r2] = *reinterpret_cast<const bf16x8*>(&Asm[(wrow + r2 * 16 + lm) * 32 + quad * 8]);
    #pragma unroll
    for (int c2 = 0; c2 < 2; ++c2)
      bfr[c2] = *reinterpret_cast<const bf16x8*>(&Bsm[(wcol + c2 * 16 + lm) * 32 + quad * 8]);
    #pragma unroll
    for (int r2 = 0; r2 < 4; ++r2)
      #pragma unroll
      for (int c2 = 0; c2 < 2; ++c2)
        acc[r2][c2] = __builtin_amdgcn_mfma_f32_16x16x32_bf16(af[r2], bfr[c2], acc[r2][c2], 0, 0, 0);
    __syncthreads();
  }

  const size_t zoff = SPLITK ? (size_t)blockIdx.z * M * N : 0;
  #pragma unroll
  for (int r2 = 0; r2 < 4; ++r2) {
    #pragma unroll
    for (int c2 = 0; c2 < 2; ++c2) {
      int col = colBase + wcol + c2 * 16 + lm;
      int row0 = rowBase + wrow + r2 * 16 + quad * 4;
      #pragma unroll
      for (int g = 0; g < 4; ++g) {
        float v = acc[r2][c2][g];
        size_t idx = (size_t)(row0 + g) * N + col;
        if (BIAS) v += bias[col];
        if (ACT == 1) v = gelu_exact(v);
        if (RES) v += resF[idx];
        if (OUTF) Cf[zoff + idx] = v;
        if (OUTB) Cb[idx] = f2us(v);
      }
    }
  }
}

// ---------- split-K reduce for zg ----------
__global__ __launch_bounds__(256)
void reduce8_kernel(const float* __restrict__ P, const float* __restrict__ db,
                    float* __restrict__ ZG)
{
  int i = blockIdx.x * 256 + threadIdx.x;
  float s = db[i % 768];
  #pragma unroll
  for (int k = 0; k < 8; ++k) s += P[i + k * 786432];
  ZG[i] = s;
}

// ---------- MFMA fused attention: one block per (seq, head), causal ----------
// QKV packed bf16 [nseq*L, DS]; Y bf16 [nseq*L, DY]. NW waves, wave = one 16-row tile.
template<int L, int HD, int NW>
__global__ __launch_bounds__(NW * 64)
void fattn(const ushort* __restrict__ QKV, ushort* __restrict__ Yp,
           int nh, int DS, int DY, int offQ, int offK, int offV)
{
  constexpr int PQ = HD + 8;   // Q/K row pitch (ushorts)
  constexpr int PV = L + 8;    // Vt / Ps row pitch
  constexpr int KS = HD / 32;  // k-steps for S
  constexpr int NCT = L / 16;  // col tiles of S
  constexpr int KS2 = L / 32;  // k-steps for PV
  constexpr int NYT = HD / 16; // col tiles of Y
  constexpr int T = NW * 64;
  __shared__ __align__(16) ushort Ql[L * PQ];
  __shared__ __align__(16) ushort Kl[L * PQ];
  __shared__ __align__(16) ushort Vt[HD * PV];
  __shared__ __align__(16) ushort Ps[L * PV];
  const int tid = threadIdx.x;
  const int b = blockIdx.x / nh, h = blockIdx.x % nh;
  const size_t rowb = (size_t)b * L * DS;
  const int hb = h * HD;
  // stage Q,K rows (16B vectors) and V transposed (scalar)
  constexpr int CH = L * HD / 8;
  for (int idx = tid; idx < CH; idx += T) {
    int row = idx / (HD / 8), seg = idx % (HD / 8);
    uint4 q4 = *reinterpret_cast<const uint4*>(&QKV[rowb + (size_t)row * DS + offQ + hb + seg * 8]);
    *reinterpret_cast<uint4*>(&Ql[row * PQ + seg * 8]) = q4;
    uint4 k4 = *reinterpret_cast<const uint4*>(&QKV[rowb + (size_t)row * DS + offK + hb + seg * 8]);
    *reinterpret_cast<uint4*>(&Kl[row * PQ + seg * 8]) = k4;
  }
  for (int idx = tid; idx < L * HD; idx += T) {
    int j = idx / HD, d = idx % HD;
    Vt[d * PV + j] = QKV[rowb + (size_t)j * DS + offV + hb + d];
  }
  __syncthreads();
  const int lane = tid & 63;
  const int quad = lane >> 4, lm = lane & 15;
  const int rt = tid >> 6;     // row tile = wave
  const float scale = rsqrtf((float)HD);
  // S = Q K^T  (A-frag = Q rows, B-frag = K rows)
  bf16x8 af[KS];
  #pragma unroll
  for (int s = 0; s < KS; ++s)
    af[s] = *reinterpret_cast<const bf16x8*>(&Ql[(rt * 16 + lm) * PQ + s * 32 + quad * 8]);
  f32x4 sacc[NCT] = {};
  #pragma unroll
  for (int ct = 0; ct < NCT; ++ct)
    #pragma unroll
    for (int s = 0; s < KS; ++s) {
      bf16x8 bf = *reinterpret_cast<const bf16x8*>(&Kl[(ct * 16 + lm) * PQ + s * 32 + quad * 8]);
      sacc[ct] = __builtin_amdgcn_mfma_f32_16x16x32_bf16(af[s], bf, sacc[ct], 0, 0, 0);
    }
  // causal softmax; C layout: row = rt*16+quad*4+g, col = ct*16+lm
  float inv[4];
  #pragma unroll
  for (int g = 0; g < 4; ++g) {
    const int row = rt * 16 + quad * 4 + g;
    float sv[NCT]; float m = -1e30f;
    #pragma unroll
    for (int ct = 0; ct < NCT; ++ct) {
      int col = ct * 16 + lm;
      float x = sacc[ct][g] * scale;
      sv[ct] = (col <= row) ? x : -1e30f;
      m = fmaxf(m, sv[ct]);
    }
    #pragma unroll
    for (int off = 8; off >= 1; off >>= 1) m = fmaxf(m, __shfl_xor(m, off));
    float l = 0.f;
    #pragma unroll
    for (int ct = 0; ct < NCT; ++ct) {
      float p = __expf(sv[ct] - m);
      l += p;
      Ps[row * PV + ct * 16 + lm] = f2us(p);
    }
    #pragma unroll
    for (int off = 8; off >= 1; off >>= 1) l += __shfl_xor(l, off);
    inv[g] = 1.f / l;
  }
  __syncthreads();
  // Y = P V  (A-frag = Ps rows, B-frag = Vt rows)
  f32x4 yacc[NYT] = {};
  #pragma unroll
  for (int s = 0; s < KS2; ++s) {
    bf16x8 ap = *reinterpret_cast<const bf16x8*>(&Ps[(rt * 16 + lm) * PV + s * 32 + quad * 8]);
    #pragma unroll
    for (int ct = 0; ct < NYT; ++ct) {
      bf16x8 bv = *reinterpret_cast<const bf16x8*>(&Vt[(ct * 16 + lm) * PV + s * 32 + quad * 8]);
      yacc[ct] = __builtin_amdgcn_mfma_f32_16x16x32_bf16(ap, bv, yacc[ct], 0, 0, 0);
    }
  }
  #pragma unroll
  for (int ct = 0; ct < NYT; ++ct)
    #pragma unroll
    for (int g = 0; g < 4; ++g) {
      int row = rt * 16 + quad * 4 + g;
      int d = ct * 16 + lm;
      Yp[((size_t)b * L + row) * DY + hb + d] = f2us(yacc[ct][g] * inv[g]);
    }
}

// ---------- zg interleave (fp32) ----------
__global__ __launch_bounds__(256)
void interleave_kernel(const float* __restrict__ zg, const float* __restrict__ xg,
                       float* __restrict__ z)
{
  int idx = blockIdx.x * 256 + threadIdx.x;
  int c = idx % 768;
  int tok = idx / 768;
  int b = tok / 96, r = tok % 96;
  int n = r / 3, t = r % 3;
  z[idx] = (t == 0) ? zg[((size_t)b * 32 + n) * 768 + c]
                    : xg[((size_t)b * 64 + 2 * n + (t - 1)) * 768 + c];
}

// ---------- final gather (fp32) ----------
__global__ __launch_bounds__(256)
void gather_kernel(const float* __restrict__ zfin, float* __restrict__ dst)
{
  int idx = blockIdx.x * 256 + threadIdx.x;
  int c = idx % 768;
  int t = (idx / 768) % 64;
  int b = idx / (768 * 64);
  int n = t >> 1, s = t & 1;
  dst[idx] = zfin[((size_t)b * 96 + 3 * n + 1 + s) * 768 + c];
}

extern "C" void kernel_launch(void* const* d_in, const int* in_sizes, int n_in,
                              void* d_out, int out_size, void* d_ws, size_t ws_size,
                              hipStream_t stream) {
  const float* xl = (const float*)d_in[0];
  const float* xg = (const float*)d_in[1];
  const float* l_ln1_w = (const float*)d_in[2];  const float* l_ln1_b = (const float*)d_in[3];
  const float* l_ln2_w = (const float*)d_in[4];  const float* l_ln2_b = (const float*)d_in[5];
  const float* l_wq = (const float*)d_in[6];     const float* l_bq = (const float*)d_in[7];
  const float* l_wk = (const float*)d_in[8];     const float* l_bk = (const float*)d_in[9];
  const float* l_wv = (const float*)d_in[10];    const float* l_bv = (const float*)d_in[11];
  const float* l_wo = (const float*)d_in[12];    const float* l_bo = (const float*)d_in[13];
  const float* l_w1 = (const float*)d_in[14];    const float* l_b1 = (const float*)d_in[15];
  const float* l_w2 = (const float*)d_in[16];    const float* l_b2 = (const float*)d_in[17];
  const float* g_ln1_w = (const float*)d_in[18]; const float* g_ln1_b = (const float*)d_in[19];
  const float* g_ln2_w = (const float*)d_in[20]; const float* g_ln2_b = (const float*)d_in[21];
  const float* g_wq = (const float*)d_in[22];    const float* g_bq = (const float*)d_in[23];
  const float* g_wk = (const float*)d_in[24];    const float* g_bk = (const float*)d_in[25];
  const float* g_wv = (const float*)d_in[26];    const float* g_bv = (const float*)d_in[27];
  const float* g_wo = (const float*)d_in[28];    const float* g_bo = (const float*)d_in[29];
  const float* g_w1 = (const float*)d_in[30];    const float* g_b1 = (const float*)d_in[31];
  const float* g_w2 = (const float*)d_in[32];    const float* g_b2 = (const float*)d_in[33];
  const float* dw   = (const float*)d_in[34];    const float* db   = (const float*)d_in[35];

  float* outL = (float*)d_out;
  float* outG = outL + 12582912;

  char* W = (char*)d_ws;
  ushort* A_bf   = (ushort*)(W + 0);
  ushort* QKVl   = (ushort*)(W + 25165824);
  ushort* HIDl   = (ushort*)(W + 25165824);
  ushort* XLb    = (ushort*)(W + 75497472);
  float*  X1     = (float*)(W + 100663296);
  ushort* wqkv_t = (ushort*)(W + 150994944);
  ushort* wo_t   = (ushort*)(W + 151216128);
  ushort* w1_t   = (ushort*)(W + 151289856);
  ushort* w2_t   = (ushort*)(W + 151584768);
  ushort* wd_t   = (ushort*)(W + 151879680);
  ushort* wgqkv_t= (ushort*)(W + 170754048);
  ushort* wgo_t  = (ushort*)(W + 174292992);
  ushort* wg1_t  = (ushort*)(W + 175472640);
  ushort* wg2_t  = (ushort*)(W + 180191232);
  float*  bqkv_l = (float*)(W + 184909824);
  float*  bqkv_g = (float*)(W + 184912128);
  float*  ZGP  = (float*)(W + 0);
  float*  ZG   = (float*)(W + 25165824);
  float*  Z    = (float*)(W + 28311552);
  ushort* LNG  = (ushort*)(W + 37748736);
  ushort* QKVg = (ushort*)(W + 42467328);
  ushort* YG   = (ushort*)(W + 56623104);
  float*  X1G  = (float*)(W + 61341696);
  ushort* HLNG = (ushort*)(W + 70778880);
  ushort* HIDg = (ushort*)(W + 100663296);
  float*  OUTG = (float*)(W + 119537664);

  // ---- weight conversion + bias packs ----
  transp_kernel<<<dim3(3,3),   256, 0, stream>>>(l_wq, wqkv_t, 192, 192, 192, 0);
  transp_kernel<<<dim3(3,3),   256, 0, stream>>>(l_wk, wqkv_t, 192, 192, 192, 192);
  transp_kernel<<<dim3(3,3),   256, 0, stream>>>(l_wv, wqkv_t, 192, 192, 192, 384);
  transp_kernel<<<dim3(3,3),   256, 0, stream>>>(l_wo, wo_t,   192, 192, 192, 0);
  transp_kernel<<<dim3(12,3),  256, 0, stream>>>(l_w1, w1_t,   192, 768, 192, 0);
  transp_kernel<<<dim3(3,12),  256, 0, stream>>>(l_w2, w2_t,   768, 192, 768, 0);
  transp_kernel<<<dim3(12,192),256, 0, stream>>>(dw,   wd_t,   12288, 768, 12288, 0);
  transp_kernel<<<dim3(12,12), 256, 0, stream>>>(g_wq, wgqkv_t, 768, 768, 768, 0);
  transp_kernel<<<dim3(12,12), 256, 0, stream>>>(g_wk, wgqkv_t, 768, 768, 768, 768);
  transp_kernel<<<dim3(12,12), 256, 0, stream>>>(g_wv, wgqkv_t, 768, 768, 768, 1536);
  transp_kernel<<<dim3(12,12), 256, 0, stream>>>(g_wo, wgo_t,  768, 768, 768, 0);
  transp_kernel<<<dim3(48,12), 256, 0, stream>>>(g_w1, wg1_t,  768, 3072, 768, 0);
  transp_kernel<<<dim3(12,48), 256, 0, stream>>>(g_w2, wg2_t,  3072, 768, 3072, 0);
  pack3_kernel<<<3, 256, 0, stream>>>(bqkv_l, l_bq, 192, l_bk, 192, l_bv, 192);
  pack3_kernel<<<9, 256, 0, stream>>>(bqkv_g, g_bq, 768, g_bk, 768, g_bv, 768);

  // ---- local block ----
  ln_kernel<192><<<16384, 256, 0, stream>>>(xl, l_ln1_w, l_ln1_b, A_bf, 65536);
  mgemm<0,0,0,1,1,0><<<dim3(9,512), 256, 0, stream>>>(A_bf, wqkv_t, bqkv_l, nullptr, nullptr, QKVl, 65536, 576, 192, 0);
  fattn<64,32,4><<<6144, 256, 0, stream>>>(QKVl, A_bf, 6, 576, 192, 0, 192, 384);
  mgemm<0,1,1,0,1,0><<<dim3(3,512), 256, 0, stream>>>(A_bf, wo_t, l_bo, xl, X1, nullptr, 65536, 192, 192, 0);
  ln_kernel<192><<<16384, 256, 0, stream>>>(X1, l_ln2_w, l_ln2_b, A_bf, 65536);
  for (int h = 0; h < 2; ++h) {
    size_t ro = (size_t)h * 32768 * 192;
    mgemm<1,0,0,1,1,0><<<dim3(12,256), 256, 0, stream>>>(A_bf + ro, w1_t, l_b1, nullptr, nullptr, HIDl, 32768, 768, 192, 0);
    mgemm<0,1,1,1,1,0><<<dim3(3,256), 256, 0, stream>>>(HIDl, w2_t, l_b2, X1 + ro, outL + ro, XLb + ro, 32768, 192, 768, 0);
  }
  // ---- group summary projection (split-K=8) + interleave ----
  mgemm<0,0,1,0,0,1><<<dim3(12,8,8), 256, 0, stream>>>(XLb, wd_t, nullptr, nullptr, ZGP, nullptr, 1024, 768, 12288, 1536);
  reduce8_kernel<<<3072, 256, 0, stream>>>(ZGP, db, ZG);
  interleave_kernel<<<9216, 256, 0, stream>>>(ZG, xg, Z);
  // ---- global block ----
  ln_kernel<768><<<768, 256, 0, stream>>>(Z, g_ln1_w, g_ln1_b, LNG, 3072);
  mgemm<0,0,0,1,1,0><<<dim3(36,24), 256, 0, stream>>>(LNG, wgqkv_t, bqkv_g, nullptr, nullptr, QKVg, 3072, 2304, 768, 0);
  fattn<96,64,6><<<384, 384, 0, stream>>>(QKVg, YG, 12, 2304, 768, 0, 768, 1536);
  mgemm<0,1,1,0,1,0><<<dim3(12,24), 256, 0, stream>>>(YG, wgo_t, g_bo, Z, X1G, nullptr, 3072, 768, 768, 0);
  ln_kernel<768><<<768, 256, 0, stream>>>(X1G, g_ln2_w, g_ln2_b, HLNG, 3072);
  mgemm<1,0,0,1,1,0><<<dim3(48,24), 256, 0, stream>>>(HLNG, wg1_t, g_b1, nullptr, nullptr, HIDg, 3072, 3072, 768, 0);
  mgemm<0,1,1,0,1,0><<<dim3(12,24), 256, 0, stream>>>(HIDg, wg2_t, g_b2, X1G, OUTG, nullptr, 3072, 768, 3072, 0);
  gather_kernel<<<6144, 256, 0, stream>>>(OUTG, outG);
}

// Round 5
// 700.364 us; speedup vs baseline: 4.8902x; 1.0591x over previous
//
#include <hip/hip_runtime.h>
#include <hip/hip_bf16.h>

// StARformer round 4: 128x128 MFMA GEMM for all big/global shapes, split-K on
// deep-K GEMMs, batched weight transpose (1 launch), MFMA fused attention.

typedef unsigned short ushort;
typedef __bf16 bf16x8 __attribute__((ext_vector_type(8)));
typedef float f32x4 __attribute__((ext_vector_type(4)));

__device__ __forceinline__ ushort f2us(float f) {
  __hip_bfloat16 h = __float2bfloat16(f);
  return *reinterpret_cast<ushort*>(&h);
}
__device__ __forceinline__ float gelu_exact(float v) {
  return 0.5f * v * (1.f + erff(v * 0.70710678118654752f));
}
__device__ __forceinline__ void gload16(const ushort* g, ushort* l) {
  __builtin_amdgcn_global_load_lds(
      (const __attribute__((address_space(1))) void*)g,
      (__attribute__((address_space(3))) void*)l, 16, 0, 0);
}

// ---------- batched transpose+convert: 13 weight jobs in one launch ----------
struct TJobs { const float* s[13]; ushort* d[13]; };

__global__ __launch_bounds__(256)
void transp_all(TJobs J)
{
  // job dims (K=src rows, N=src cols); dst[(rowOff+n)*stride + k] = bf16(src[k*N+n])
  static constexpr int NN[13]  = {192,192,192,192,768,192,768,768,768,768,768,3072,768};
  static constexpr int SS[13]  = {192,192,192,192,192,768,12288,768,768,768,768,768,3072};
  static constexpr int RO[13]  = {0,192,384,0,0,0,0,0,768,1536,0,0,0};
  static constexpr int CUM[14] = {0,9,18,27,36,72,108,2412,2556,2700,2844,2988,3564,4140};
  __shared__ float t[64][65];
  int bid = blockIdx.x;
  int j = 0;
  while (bid >= CUM[j + 1]) ++j;
  int tIdx = bid - CUM[j];
  const int N = NN[j], stride = SS[j], rowOff = RO[j];
  const int nx = N >> 6;
  const int n0 = (tIdx % nx) * 64, k0 = (tIdx / nx) * 64;
  const float* W = J.s[j];
  ushort* Wt = J.d[j];
  int c = threadIdx.x & 63, r = threadIdx.x >> 6;
  #pragma unroll
  for (int i = 0; i < 16; ++i) {
    int kr = r + i * 4;
    t[kr][c] = W[(size_t)(k0 + kr) * N + n0 + c];
  }
  __syncthreads();
  #pragma unroll
  for (int i = 0; i < 16; ++i) {
    int nr = r + i * 4;
    Wt[(size_t)(rowOff + n0 + nr) * stride + k0 + c] = f2us(t[c][nr]);
  }
}

// ---------- pack 3 bias vectors ----------
__global__ __launch_bounds__(256)
void pack3_kernel(float* dst, const float* a, int na, const float* b, int nb,
                  const float* c, int nc)
{
  int i = blockIdx.x * 256 + threadIdx.x;
  if (i >= na + nb + nc) return;
  dst[i] = (i < na) ? a[i] : (i < na + nb ? b[i - na] : c[i - na - nb]);
}

// ---------- LayerNorm: one wave per row, fp32 in, bf16 out ----------
template<int D>
__global__ __launch_bounds__(256)
void ln_kernel(const float* __restrict__ x, const float* __restrict__ g,
               const float* __restrict__ bb, ushort* __restrict__ out, int rows)
{
  int wave = threadIdx.x >> 6, lane = threadIdx.x & 63;
  int row = blockIdx.x * 4 + wave;
  if (row >= rows) return;
  const float* xr = x + (size_t)row * D;
  constexpr int E = D / 64;
  float vals[E];
  float s = 0.f;
  #pragma unroll
  for (int e = 0; e < E; ++e) { vals[e] = xr[e * 64 + lane]; s += vals[e]; }
  #pragma unroll
  for (int off = 32; off >= 1; off >>= 1) s += __shfl_xor(s, off);
  float m = s * (1.f / D);
  float s2 = 0.f;
  #pragma unroll
  for (int e = 0; e < E; ++e) { float d = vals[e] - m; s2 += d * d; }
  #pragma unroll
  for (int off = 32; off >= 1; off >>= 1) s2 += __shfl_xor(s2, off);
  float rstd = rsqrtf(s2 * (1.f / D) + 1e-5f);
  ushort* orow = out + (size_t)row * D;
  #pragma unroll
  for (int e = 0; e < E; ++e) {
    int c = e * 64 + lane;
    orow[c] = f2us((vals[e] - m) * rstd * g[c] + bb[c]);
  }
}

// ---------- MFMA GEMM 128x64: BM=128 BN=64 BK=32, 4 waves (2x2) ----------
template<int ACT, int RES, int OUTF, int OUTB, int BIAS>
__global__ __launch_bounds__(256)
void mgemm(const ushort* __restrict__ A, const ushort* __restrict__ Bt,
           const float* __restrict__ bias, const float* __restrict__ resF,
           float* __restrict__ Cf, ushort* __restrict__ Cb,
           int M, int N, int K)
{
  __shared__ __align__(16) ushort Asm[128 * 32];
  __shared__ __align__(16) ushort Bsm[64 * 32];
  const int tid = threadIdx.x;
  const int wave = tid >> 6, lane = tid & 63;
  const int quad = lane >> 4, lm = lane & 15;
  const int rowBase = blockIdx.y * 128, colBase = blockIdx.x * 64;
  const int wrow = (wave & 1) * 64, wcol = (wave >> 1) * 32;
  const int srow = lane >> 2, skcol = (lane & 3) * 8;

  f32x4 acc[4][2] = {};
  for (int k0 = 0; k0 < K; k0 += 32) {
    #pragma unroll
    for (int uu = 0; uu < 3; ++uu) {
      int u = wave * 3 + uu;
      if (u < 8) {
        const ushort* gp = A + (size_t)(rowBase + u * 16 + srow) * K + k0 + skcol;
        gload16(gp, &Asm[u * 512]);
      } else {
        int v = u - 8;
        const ushort* gp = Bt + (size_t)(colBase + v * 16 + srow) * K + k0 + skcol;
        gload16(gp, &Bsm[v * 512]);
      }
    }
    __syncthreads();
    bf16x8 af[4], bfr[2];
    #pragma unroll
    for (int r2 = 0; r2 < 4; ++r2)
      af[r2] = *reinterpret_cast<const bf16x8*>(&Asm[(wrow + r2 * 16 + lm) * 32 + quad * 8]);
    #pragma unroll
    for (int c2 = 0; c2 < 2; ++c2)
      bfr[c2] = *reinterpret_cast<const bf16x8*>(&Bsm[(wcol + c2 * 16 + lm) * 32 + quad * 8]);
    #pragma unroll
    for (int r2 = 0; r2 < 4; ++r2)
      #pragma unroll
      for (int c2 = 0; c2 < 2; ++c2)
        acc[r2][c2] = __builtin_amdgcn_mfma_f32_16x16x32_bf16(af[r2], bfr[c2], acc[r2][c2], 0, 0, 0);
    __syncthreads();
  }

  #pragma unroll
  for (int r2 = 0; r2 < 4; ++r2) {
    #pragma unroll
    for (int c2 = 0; c2 < 2; ++c2) {
      int col = colBase + wcol + c2 * 16 + lm;
      int row0 = rowBase + wrow + r2 * 16 + quad * 4;
      #pragma unroll
      for (int g = 0; g < 4; ++g) {
        float v = acc[r2][c2][g];
        size_t idx = (size_t)(row0 + g) * N + col;
        if (BIAS) v += bias[col];
        if (ACT == 1) v = gelu_exact(v);
        if (RES) v += resF[idx];
        if (OUTF) Cf[idx] = v;
        if (OUTB) Cb[idx] = f2us(v);
      }
    }
  }
}

// ---------- MFMA GEMM 128x128: BM=128 BN=128 BK=32, 4 waves each 64x64 ----------
// SPLITK: blockIdx.z picks K-chunk; writes fp32 partial at Cf + z*M*N (raw, no epilogue).
template<int ACT, int RES, int OUTF, int OUTB, int BIAS, int SPLITK>
__global__ __launch_bounds__(256)
void mgemm128(const ushort* __restrict__ A, const ushort* __restrict__ Bt,
              const float* __restrict__ bias, const float* __restrict__ resF,
              float* __restrict__ Cf, ushort* __restrict__ Cb,
              int M, int N, int K, int kChunk)
{
  __shared__ __align__(16) ushort Asm[128 * 32];
  __shared__ __align__(16) ushort Bsm[128 * 32];
  const int tid = threadIdx.x;
  const int wave = tid >> 6, lane = tid & 63;
  const int quad = lane >> 4, lm = lane & 15;
  const int rowBase = blockIdx.y * 128, colBase = blockIdx.x * 128;
  const int wrow = (wave & 1) * 64, wcol = (wave >> 1) * 64;
  const int srow = lane >> 2, skcol = (lane & 3) * 8;

  f32x4 acc[4][4] = {};
  const int kbeg = SPLITK ? blockIdx.z * kChunk : 0;
  const int kend = kbeg + (SPLITK ? kChunk : K);

  for (int k0 = kbeg; k0 < kend; k0 += 32) {
    #pragma unroll
    for (int uu = 0; uu < 4; ++uu) {
      int u = wave * 4 + uu;
      if (u < 8) {
        const ushort* gp = A + (size_t)(rowBase + u * 16 + srow) * K + k0 + skcol;
        gload16(gp, &Asm[u * 512]);
      } else {
        int v = u - 8;
        const ushort* gp = Bt + (size_t)(colBase + v * 16 + srow) * K + k0 + skcol;
        gload16(gp, &Bsm[v * 512]);
      }
    }
    __syncthreads();
    bf16x8 af[4], bfr[4];
    #pragma unroll
    for (int r2 = 0; r2 < 4; ++r2)
      af[r2] = *reinterpret_cast<const bf16x8*>(&Asm[(wrow + r2 * 16 + lm) * 32 + quad * 8]);
    #pragma unroll
    for (int c2 = 0; c2 < 4; ++c2)
      bfr[c2] = *reinterpret_cast<const bf16x8*>(&Bsm[(wcol + c2 * 16 + lm) * 32 + quad * 8]);
    #pragma unroll
    for (int r2 = 0; r2 < 4; ++r2)
      #pragma unroll
      for (int c2 = 0; c2 < 4; ++c2)
        acc[r2][c2] = __builtin_amdgcn_mfma_f32_16x16x32_bf16(af[r2], bfr[c2], acc[r2][c2], 0, 0, 0);
    __syncthreads();
  }

  const size_t zoff = SPLITK ? (size_t)blockIdx.z * M * N : 0;
  #pragma unroll
  for (int r2 = 0; r2 < 4; ++r2) {
    #pragma unroll
    for (int c2 = 0; c2 < 4; ++c2) {
      int col = colBase + wcol + c2 * 16 + lm;
      int row0 = rowBase + wrow + r2 * 16 + quad * 4;
      #pragma unroll
      for (int g = 0; g < 4; ++g) {
        float v = acc[r2][c2][g];
        size_t idx = (size_t)(row0 + g) * N + col;
        if (BIAS) v += bias[col];
        if (ACT == 1) v = gelu_exact(v);
        if (RES) v += resF[idx];
        if (OUTF) Cf[zoff + idx] = v;
        if (OUTB) Cb[idx] = f2us(v);
      }
    }
  }
}

// ---------- split-K reduce for zg: ZG = sum_8 P + bias ----------
__global__ __launch_bounds__(256)
void reduce8_kernel(const float* __restrict__ P, const float* __restrict__ db,
                    float* __restrict__ ZG)
{
  int i = blockIdx.x * 256 + threadIdx.x;
  float s = db[i % 768];
  #pragma unroll
  for (int k = 0; k < 8; ++k) s += P[i + k * 786432];
  ZG[i] = s;
}

// ---------- split-K reduce for global fc2: out = sum_4 P + bias + res ----------
__global__ __launch_bounds__(256)
void reduce4res_kernel(const float* __restrict__ P, const float* __restrict__ db,
                       const float* __restrict__ res, float* __restrict__ out)
{
  int i = blockIdx.x * 256 + threadIdx.x;   // 3072*768
  float s = db[i % 768] + res[i];
  #pragma unroll
  for (int k = 0; k < 4; ++k) s += P[i + k * 2359296];
  out[i] = s;
}

// ---------- MFMA fused attention: one block per (seq, head), causal ----------
template<int L, int HD, int NW>
__global__ __launch_bounds__(NW * 64)
void fattn(const ushort* __restrict__ QKV, ushort* __restrict__ Yp,
           int nh, int DS, int DY, int offQ, int offK, int offV)
{
  constexpr int PQ = HD + 8;
  constexpr int PV = L + 8;
  constexpr int KS = HD / 32;
  constexpr int NCT = L / 16;
  constexpr int KS2 = L / 32;
  constexpr int NYT = HD / 16;
  constexpr int T = NW * 64;
  __shared__ __align__(16) ushort Ql[L * PQ];
  __shared__ __align__(16) ushort Kl[L * PQ];
  __shared__ __align__(16) ushort Vt[HD * PV];
  __shared__ __align__(16) ushort Ps[L * PV];
  const int tid = threadIdx.x;
  const int b = blockIdx.x / nh, h = blockIdx.x % nh;
  const size_t rowb = (size_t)b * L * DS;
  const int hb = h * HD;
  constexpr int CH = L * HD / 8;
  for (int idx = tid; idx < CH; idx += T) {
    int row = idx / (HD / 8), seg = idx % (HD / 8);
    uint4 q4 = *reinterpret_cast<const uint4*>(&QKV[rowb + (size_t)row * DS + offQ + hb + seg * 8]);
    *reinterpret_cast<uint4*>(&Ql[row * PQ + seg * 8]) = q4;
    uint4 k4 = *reinterpret_cast<const uint4*>(&QKV[rowb + (size_t)row * DS + offK + hb + seg * 8]);
    *reinterpret_cast<uint4*>(&Kl[row * PQ + seg * 8]) = k4;
  }
  for (int idx = tid; idx < L * HD; idx += T) {
    int j = idx / HD, d = idx % HD;
    Vt[d * PV + j] = QKV[rowb + (size_t)j * DS + offV + hb + d];
  }
  __syncthreads();
  const int lane = tid & 63;
  const int quad = lane >> 4, lm = lane & 15;
  const int rt = tid >> 6;
  const float scale = rsqrtf((float)HD);
  bf16x8 af[KS];
  #pragma unroll
  for (int s = 0; s < KS; ++s)
    af[s] = *reinterpret_cast<const bf16x8*>(&Ql[(rt * 16 + lm) * PQ + s * 32 + quad * 8]);
  f32x4 sacc[NCT] = {};
  #pragma unroll
  for (int ct = 0; ct < NCT; ++ct)
    #pragma unroll
    for (int s = 0; s < KS; ++s) {
      bf16x8 bf = *reinterpret_cast<const bf16x8*>(&Kl[(ct * 16 + lm) * PQ + s * 32 + quad * 8]);
      sacc[ct] = __builtin_amdgcn_mfma_f32_16x16x32_bf16(af[s], bf, sacc[ct], 0, 0, 0);
    }
  float inv[4];
  #pragma unroll
  for (int g = 0; g < 4; ++g) {
    const int row = rt * 16 + quad * 4 + g;
    float sv[NCT]; float m = -1e30f;
    #pragma unroll
    for (int ct = 0; ct < NCT; ++ct) {
      int col = ct * 16 + lm;
      float x = sacc[ct][g] * scale;
      sv[ct] = (col <= row) ? x : -1e30f;
      m = fmaxf(m, sv[ct]);
    }
    #pragma unroll
    for (int off = 8; off >= 1; off >>= 1) m = fmaxf(m, __shfl_xor(m, off));
    float l = 0.f;
    #pragma unroll
    for (int ct = 0; ct < NCT; ++ct) {
      float p = __expf(sv[ct] - m);
      l += p;
      Ps[row * PV + ct * 16 + lm] = f2us(p);
    }
    #pragma unroll
    for (int off = 8; off >= 1; off >>= 1) l += __shfl_xor(l, off);
    inv[g] = 1.f / l;
  }
  __syncthreads();
  f32x4 yacc[NYT] = {};
  #pragma unroll
  for (int s = 0; s < KS2; ++s) {
    bf16x8 ap = *reinterpret_cast<const bf16x8*>(&Ps[(rt * 16 + lm) * PV + s * 32 + quad * 8]);
    #pragma unroll
    for (int ct = 0; ct < NYT; ++ct) {
      bf16x8 bv = *reinterpret_cast<const bf16x8*>(&Vt[(ct * 16 + lm) * PV + s * 32 + quad * 8]);
      yacc[ct] = __builtin_amdgcn_mfma_f32_16x16x32_bf16(ap, bv, yacc[ct], 0, 0, 0);
    }
  }
  #pragma unroll
  for (int ct = 0; ct < NYT; ++ct)
    #pragma unroll
    for (int g = 0; g < 4; ++g) {
      int row = rt * 16 + quad * 4 + g;
      int d = ct * 16 + lm;
      Yp[((size_t)b * L + row) * DY + hb + d] = f2us(yacc[ct][g] * inv[g]);
    }
}

// ---------- zg interleave (fp32) ----------
__global__ __launch_bounds__(256)
void interleave_kernel(const float* __restrict__ zg, const float* __restrict__ xg,
                       float* __restrict__ z)
{
  int idx = blockIdx.x * 256 + threadIdx.x;
  int c = idx % 768;
  int tok = idx / 768;
  int b = tok / 96, r = tok % 96;
  int n = r / 3, t = r % 3;
  z[idx] = (t == 0) ? zg[((size_t)b * 32 + n) * 768 + c]
                    : xg[((size_t)b * 64 + 2 * n + (t - 1)) * 768 + c];
}

// ---------- final gather (fp32) ----------
__global__ __launch_bounds__(256)
void gather_kernel(const float* __restrict__ zfin, float* __restrict__ dst)
{
  int idx = blockIdx.x * 256 + threadIdx.x;
  int c = idx % 768;
  int t = (idx / 768) % 64;
  int b = idx / (768 * 64);
  int n = t >> 1, s = t & 1;
  dst[idx] = zfin[((size_t)b * 96 + 3 * n + 1 + s) * 768 + c];
}

extern "C" void kernel_launch(void* const* d_in, const int* in_sizes, int n_in,
                              void* d_out, int out_size, void* d_ws, size_t ws_size,
                              hipStream_t stream) {
  const float* xl = (const float*)d_in[0];
  const float* xg = (const float*)d_in[1];
  const float* l_ln1_w = (const float*)d_in[2];  const float* l_ln1_b = (const float*)d_in[3];
  const float* l_ln2_w = (const float*)d_in[4];  const float* l_ln2_b = (const float*)d_in[5];
  const float* l_wq = (const float*)d_in[6];     const float* l_bq = (const float*)d_in[7];
  const float* l_wk = (const float*)d_in[8];     const float* l_bk = (const float*)d_in[9];
  const float* l_wv = (const float*)d_in[10];    const float* l_bv = (const float*)d_in[11];
  const float* l_wo = (const float*)d_in[12];    const float* l_bo = (const float*)d_in[13];
  const float* l_w1 = (const float*)d_in[14];    const float* l_b1 = (const float*)d_in[15];
  const float* l_w2 = (const float*)d_in[16];    const float* l_b2 = (const float*)d_in[17];
  const float* g_ln1_w = (const float*)d_in[18]; const float* g_ln1_b = (const float*)d_in[19];
  const float* g_ln2_w = (const float*)d_in[20]; const float* g_ln2_b = (const float*)d_in[21];
  const float* g_wq = (const float*)d_in[22];    const float* g_bq = (const float*)d_in[23];
  const float* g_wk = (const float*)d_in[24];    const float* g_bk = (const float*)d_in[25];
  const float* g_wv = (const float*)d_in[26];    const float* g_bv = (const float*)d_in[27];
  const float* g_wo = (const float*)d_in[28];    const float* g_bo = (const float*)d_in[29];
  const float* g_w1 = (const float*)d_in[30];    const float* g_b1 = (const float*)d_in[31];
  const float* g_w2 = (const float*)d_in[32];    const float* g_b2 = (const float*)d_in[33];
  const float* dw   = (const float*)d_in[34];    const float* db   = (const float*)d_in[35];

  float* outL = (float*)d_out;
  float* outG = outL + 12582912;

  char* W = (char*)d_ws;
  ushort* A_bf   = (ushort*)(W + 0);
  ushort* QKVl   = (ushort*)(W + 25165824);
  ushort* HIDl   = (ushort*)(W + 25165824);
  ushort* XLb    = (ushort*)(W + 75497472);
  float*  X1     = (float*)(W + 100663296);
  ushort* wqkv_t = (ushort*)(W + 150994944);
  ushort* wo_t   = (ushort*)(W + 151216128);
  ushort* w1_t   = (ushort*)(W + 151289856);
  ushort* w2_t   = (ushort*)(W + 151584768);
  ushort* wd_t   = (ushort*)(W + 151879680);
  ushort* wgqkv_t= (ushort*)(W + 170754048);
  ushort* wgo_t  = (ushort*)(W + 174292992);
  ushort* wg1_t  = (ushort*)(W + 175472640);
  ushort* wg2_t  = (ushort*)(W + 180191232);
  float*  bqkv_l = (float*)(W + 184909824);
  float*  bqkv_g = (float*)(W + 184912128);
  // global-phase overlays
  float*  ZGP  = (float*)(W + 0);              // zg partials [8][1024*768]
  float*  FC2P = (float*)(W + 0);              // fc2 partials [4][3072*768] (after Z dead)
  float*  ZG   = (float*)(W + 25165824);
  float*  Z    = (float*)(W + 28311552);
  ushort* LNG  = (ushort*)(W + 37748736);
  ushort* QKVg = (ushort*)(W + 42467328);
  ushort* YG   = (ushort*)(W + 56623104);
  float*  X1G  = (float*)(W + 61341696);
  ushort* HLNG = (ushort*)(W + 70778880);
  ushort* HIDg = (ushort*)(W + 100663296);
  float*  OUTG = (float*)(W + 119537664);

  // ---- weight conversion (1 launch) + bias packs ----
  TJobs tj;
  tj.s[0] = l_wq; tj.s[1] = l_wk; tj.s[2] = l_wv; tj.s[3] = l_wo;
  tj.s[4] = l_w1; tj.s[5] = l_w2; tj.s[6] = dw;
  tj.s[7] = g_wq; tj.s[8] = g_wk; tj.s[9] = g_wv; tj.s[10] = g_wo;
  tj.s[11] = g_w1; tj.s[12] = g_w2;
  tj.d[0] = wqkv_t; tj.d[1] = wqkv_t; tj.d[2] = wqkv_t; tj.d[3] = wo_t;
  tj.d[4] = w1_t; tj.d[5] = w2_t; tj.d[6] = wd_t;
  tj.d[7] = wgqkv_t; tj.d[8] = wgqkv_t; tj.d[9] = wgqkv_t; tj.d[10] = wgo_t;
  tj.d[11] = wg1_t; tj.d[12] = wg2_t;
  transp_all<<<4140, 256, 0, stream>>>(tj);
  pack3_kernel<<<3, 256, 0, stream>>>(bqkv_l, l_bq, 192, l_bk, 192, l_bv, 192);
  pack3_kernel<<<9, 256, 0, stream>>>(bqkv_g, g_bq, 768, g_bk, 768, g_bv, 768);

  // ---- local block ----
  ln_kernel<192><<<16384, 256, 0, stream>>>(xl, l_ln1_w, l_ln1_b, A_bf, 65536);
  mgemm<0,0,0,1,1><<<dim3(9,512), 256, 0, stream>>>(A_bf, wqkv_t, bqkv_l, nullptr, nullptr, QKVl, 65536, 576, 192);
  fattn<64,32,4><<<6144, 256, 0, stream>>>(QKVl, A_bf, 6, 576, 192, 0, 192, 384);
  mgemm<0,1,1,0,1><<<dim3(3,512), 256, 0, stream>>>(A_bf, wo_t, l_bo, xl, X1, nullptr, 65536, 192, 192);
  ln_kernel<192><<<16384, 256, 0, stream>>>(X1, l_ln2_w, l_ln2_b, A_bf, 65536);
  for (int h = 0; h < 2; ++h) {
    size_t ro = (size_t)h * 32768 * 192;
    mgemm128<1,0,0,1,1,0><<<dim3(6,256), 256, 0, stream>>>(A_bf + ro, w1_t, l_b1, nullptr, nullptr, HIDl, 32768, 768, 192, 0);
    mgemm<0,1,1,1,1><<<dim3(3,256), 256, 0, stream>>>(HIDl, w2_t, l_b2, X1 + ro, outL + ro, XLb + ro, 32768, 192, 768);
  }
  // ---- group summary projection (128-tile, split-K=8) + interleave ----
  mgemm128<0,0,1,0,0,1><<<dim3(6,8,8), 256, 0, stream>>>(XLb, wd_t, nullptr, nullptr, ZGP, nullptr, 1024, 768, 12288, 1536);
  reduce8_kernel<<<3072, 256, 0, stream>>>(ZGP, db, ZG);
  interleave_kernel<<<9216, 256, 0, stream>>>(ZG, xg, Z);
  // ---- global block ----
  ln_kernel<768><<<768, 256, 0, stream>>>(Z, g_ln1_w, g_ln1_b, LNG, 3072);
  mgemm128<0,0,0,1,1,0><<<dim3(18,24), 256, 0, stream>>>(LNG, wgqkv_t, bqkv_g, nullptr, nullptr, QKVg, 3072, 2304, 768, 0);
  fattn<96,64,6><<<384, 384, 0, stream>>>(QKVg, YG, 12, 2304, 768, 0, 768, 1536);
  mgemm<0,1,1,0,1><<<dim3(12,24), 256, 0, stream>>>(YG, wgo_t, g_bo, Z, X1G, nullptr, 3072, 768, 768);
  ln_kernel<768><<<768, 256, 0, stream>>>(X1G, g_ln2_w, g_ln2_b, HLNG, 3072);
  mgemm128<1,0,0,1,1,0><<<dim3(24,24), 256, 0, stream>>>(HLNG, wg1_t, g_b1, nullptr, nullptr, HIDg, 3072, 3072, 768, 0);
  mgemm128<0,0,1,0,0,1><<<dim3(6,24,4), 256, 0, stream>>>(HIDg, wg2_t, nullptr, nullptr, FC2P, nullptr, 3072, 768, 3072, 768);
  reduce4res_kernel<<<9216, 256, 0, stream>>>(FC2P, g_b2, X1G, OUTG);
  gather_kernel<<<6144, 256, 0, stream>>>(OUTG, outG);
}